// Round 11
// baseline (1289.208 us; speedup 1.0000x reference)
//
#include <hip/hip_runtime.h>
#include <hip/hip_bf16.h>

#define BB 8
#define NN 4096
#define DIN 128
#define DOUT 256
#define SS 1024
#define KK 16

// Workspace in device globals: immune to ws_size, graph-capture-safe.
__device__ float g_g[(size_t)BB * NN * DOUT];     // 32 MB: g = feat @ W^T + b
__device__ int   g_knn[BB * SS * KK];
__device__ int   g_wcount[BB * NN];
__device__ float g_S1[DOUT];
__device__ float g_S2[DOUT];

typedef float f32x2 __attribute__((ext_vector_type(2)));

__device__ __forceinline__ unsigned long long umax64(unsigned long long a, unsigned long long b) {
    return a > b ? a : b;
}
__device__ __forceinline__ f32x2 pk_add(f32x2 a, f32x2 b) {
    f32x2 d; asm("v_pk_add_f32 %0, %1, %2" : "=v"(d) : "v"(a), "v"(b)); return d;
}
__device__ __forceinline__ f32x2 pk_mul(f32x2 a, f32x2 b) {
    f32x2 d; asm("v_pk_mul_f32 %0, %1, %2" : "=v"(d) : "v"(a), "v"(b)); return d;
}
__device__ __forceinline__ f32x2 pk_fma(f32x2 a, f32x2 b, f32x2 c) {
    f32x2 d; asm("v_pk_fma_f32 %0, %1, %2, %3" : "=v"(d) : "v"(a), "v"(b), "v"(c)); return d;
}
// Barrier that drains ONLY lgkm (LDS) — lets tid0's global winner-store float
// until kernel end (nothing in-kernel reads `out`). "memory" clobber orders
// all LDS ops across it at IR level.
__device__ __forceinline__ void lgkm_barrier() {
    asm volatile("s_waitcnt lgkmcnt(0)\n\ts_barrier" ::: "memory");
}

// ---------------------------------------------------------------------------
// Kernel 1 (1024 threads): blocks [0,8)   : FPS per batch (4 pts/thread,
//                             16 waves = 4/SIMD for max latency hiding)
//                          blocks [8,2056): GEMM (512 active thr, validated r2)
//                          blocks [2056,2088): zero wcount / S1 / S2
// ---------------------------------------------------------------------------
__global__ __launch_bounds__(1024) void k_fused1(
    const float* __restrict__ feat, const float* __restrict__ xyz,
    const float* __restrict__ W, const float* __restrict__ bias,
    float* __restrict__ out)
{
    __shared__ __align__(16) float smem[16384]; // xyz as float4[4096] OR gemm tiles
    __shared__ __align__(16) unsigned long long swk64[2][16];

    if (blockIdx.x < BB) {
        #pragma clang fp contract(off)
        // FPS. dist64 updates are bit-identical to numpy float64:
        // dx = (f64)x - (f64)lx; m = dx*dx (unfused); d = (m1+m2)+m3; min.
        // Selection key: top-52 bits of f64 dist | (4095-idx): argmax with
        // first-occurrence tie-break (np.argmax semantics).
        const int b = blockIdx.x, tid = threadIdx.x;
        const float* bx = xyz + (size_t)b * NN * 3;
        for (int i = 0; i < 4; ++i) {
            int p = tid + i * 1024;
            float4 v; v.x = bx[p*3]; v.y = bx[p*3+1]; v.z = bx[p*3+2]; v.w = 0.f;
            ((float4*)smem)[p] = v;
        }
        __syncthreads();
        f32x2 px2[2], py2[2], pz2[2];
        double dist64[4];
        float thr[4];
        unsigned long long key[4];
        const int gbase = tid * 4;
        const unsigned long long D0 =
            ((unsigned long long)__double_as_longlong(1e10)) & ~0xFFFULL;
        const float THR0 = __uint_as_float(__float_as_uint(1e10f) + 16u);
        #pragma unroll
        for (int pp = 0; pp < 2; ++pp) {
            float4 v0 = ((float4*)smem)[gbase + 2*pp];
            float4 v1 = ((float4*)smem)[gbase + 2*pp + 1];
            px2[pp].x = v0.x; px2[pp].y = v1.x;
            py2[pp].x = v0.y; py2[pp].y = v1.y;
            pz2[pp].x = v0.z; pz2[pp].y = v1.z;
            dist64[2*pp]   = 1e10; dist64[2*pp+1] = 1e10;
            thr[2*pp] = THR0;      thr[2*pp+1] = THR0;
            key[2*pp]   = D0 | (unsigned long long)(4095 - (gbase + 2*pp));
            key[2*pp+1] = D0 | (unsigned long long)(4095 - (gbase + 2*pp + 1));
        }
        float4 c0v = ((float4*)smem)[0];
        float lxf = c0v.x, lyf = c0v.y, lzf = c0v.z;
        float* oxyz = out + (size_t)BB * SS * DOUT;
        if (tid == 0) {
            oxyz[(size_t)(b*SS)*3]   = lxf;
            oxyz[(size_t)(b*SS)*3+1] = lyf;
            oxyz[(size_t)(b*SS)*3+2] = lzf;
        }
        for (int s = 1; s < SS; ++s) {
            const int sl = s & 1;
            const double lxd = (double)lxf, lyd = (double)lyf, lzd = (double)lzf;
            f32x2 nlx; nlx.x = -lxf; nlx.y = -lxf;
            f32x2 nly; nly.x = -lyf; nly.y = -lyf;
            f32x2 nlz; nlz.x = -lzf; nlz.y = -lzf;
            #pragma unroll
            for (int pp = 0; pp < 2; ++pp) {
                f32x2 dx = pk_add(px2[pp], nlx);
                f32x2 dy = pk_add(py2[pp], nly);
                f32x2 dz = pk_add(pz2[pp], nlz);
                f32x2 d2 = pk_mul(dx, dx);
                d2 = pk_fma(dy, dy, d2);
                d2 = pk_fma(dz, dz, d2);
                // gate: enter exact path only if d32 < f32(dist64)+16ulp
                if (d2.x < thr[2*pp]) {
                    const int r = 2*pp;
                    double ddx = (double)px2[pp].x - lxd;
                    double ddy = (double)py2[pp].x - lyd;
                    double ddz = (double)pz2[pp].x - lzd;
                    double m1 = ddx*ddx, m2 = ddy*ddy, m3 = ddz*ddz;
                    double d = (m1 + m2) + m3;
                    if (d < dist64[r]) {
                        dist64[r] = d;
                        thr[r] = __uint_as_float(__float_as_uint((float)d) + 16u);
                        key[r] = (((unsigned long long)__double_as_longlong(d)) & ~0xFFFULL)
                                 | (unsigned long long)(4095 - (gbase + r));
                    }
                }
                if (d2.y < thr[2*pp+1]) {
                    const int r = 2*pp + 1;
                    double ddx = (double)px2[pp].y - lxd;
                    double ddy = (double)py2[pp].y - lyd;
                    double ddz = (double)pz2[pp].y - lzd;
                    double m1 = ddx*ddx, m2 = ddy*ddy, m3 = ddz*ddz;
                    double d = (m1 + m2) + m3;
                    if (d < dist64[r]) {
                        dist64[r] = d;
                        thr[r] = __uint_as_float(__float_as_uint((float)d) + 16u);
                        key[r] = (((unsigned long long)__double_as_longlong(d)) & ~0xFFFULL)
                                 | (unsigned long long)(4095 - (gbase + r));
                    }
                }
            }
            // --- per-thread 4 -> 1 key max ---
            unsigned long long kk = umax64(umax64(key[0], key[1]),
                                           umax64(key[2], key[3]));
            // --- wave64 max via DPP (VALU latency, no ds_swizzle) ---
#define DPP64(CTRL) { \
    int _lo = __builtin_amdgcn_update_dpp(0, (int)(unsigned)kk, CTRL, 0xf, 0xf, true); \
    int _hi = __builtin_amdgcn_update_dpp(0, (int)(unsigned)(kk >> 32), CTRL, 0xf, 0xf, true); \
    unsigned long long _o = (((unsigned long long)(unsigned)_hi) << 32) | (unsigned)_lo; \
    if (_o > kk) kk = _o; }
            DPP64(0x111)  // row_shr:1
            DPP64(0x112)  // row_shr:2
            DPP64(0x114)  // row_shr:4
            DPP64(0x118)  // row_shr:8
            DPP64(0x142)  // row_bcast:15
            DPP64(0x143)  // row_bcast:31
#undef DPP64
            if ((tid & 63) == 63) swk64[sl][tid >> 6] = kk;
            lgkm_barrier();
            const unsigned long long* sw = swk64[sl];
            ulonglong2 q0 = ((const ulonglong2*)sw)[0];
            ulonglong2 q1 = ((const ulonglong2*)sw)[1];
            ulonglong2 q2 = ((const ulonglong2*)sw)[2];
            ulonglong2 q3 = ((const ulonglong2*)sw)[3];
            ulonglong2 q4 = ((const ulonglong2*)sw)[4];
            ulonglong2 q5 = ((const ulonglong2*)sw)[5];
            ulonglong2 q6 = ((const ulonglong2*)sw)[6];
            ulonglong2 q7 = ((const ulonglong2*)sw)[7];
            unsigned long long m0 = umax64(umax64(q0.x, q0.y), umax64(q1.x, q1.y));
            unsigned long long m1 = umax64(umax64(q2.x, q2.y), umax64(q3.x, q3.y));
            unsigned long long m2 = umax64(umax64(q4.x, q4.y), umax64(q5.x, q5.y));
            unsigned long long m3 = umax64(umax64(q6.x, q6.y), umax64(q7.x, q7.y));
            unsigned long long kmax = umax64(umax64(m0, m1), umax64(m2, m3));
            int widx = 4095 - (int)(kmax & 0xFFFULL);
            float4 c = ((float4*)smem)[widx];
            lxf = c.x; lyf = c.y; lzf = c.z;
            if (tid == 0) {
                oxyz[(size_t)(b*SS+s)*3]   = c.x;
                oxyz[(size_t)(b*SS+s)*3+1] = c.y;
                oxyz[(size_t)(b*SS+s)*3+2] = c.z;
            }
        }
    } else if (blockIdx.x < BB + 2048) {
        // GEMM: BM=64, BN=64, BK=32; 512 active threads (2x4/thread, validated
        // r2). Barriers hoisted to top level: ALL 1024 threads reach them.
        int gi = blockIdx.x - BB;
        int mt = gi & 511, nt = gi >> 9;
        int rbase = mt * 64, cbase = nt * 64;
        float* As = smem;            // [64][36]
        float* Bs = smem + 64 * 36;  // [32][68]
        int tid = threadIdx.x;
        bool active = tid < 512;
        int tx = tid & 15, ty = (tid & 511) >> 4;
        int c0 = tx * 4, r0 = ty * 2;
        int lr = (tid & 511) >> 3;  // 0..63
        int lk = (tid & 7) * 4;     // 0..28
        float acc[2][4] = {{0.f,0.f,0.f,0.f},{0.f,0.f,0.f,0.f}};
        for (int kc = 0; kc < 4; ++kc) {
            __syncthreads();
            if (active) {
                float4 av = *(const float4*)&feat[(size_t)(rbase + lr) * DIN + kc*32 + lk];
                *(float4*)&As[lr * 36 + lk] = av;
                float4 wv = *(const float4*)&W[(size_t)(cbase + lr) * DIN + kc*32 + lk];
                Bs[(lk+0)*68 + lr] = wv.x;
                Bs[(lk+1)*68 + lr] = wv.y;
                Bs[(lk+2)*68 + lr] = wv.z;
                Bs[(lk+3)*68 + lr] = wv.w;
            }
            __syncthreads();
            if (active) {
                const float* Ar0 = &As[r0 * 36];
                const float* Ar1 = Ar0 + 36;
                #pragma unroll
                for (int k = 0; k < 32; ++k) {
                    float a0 = Ar0[k], a1 = Ar1[k];
                    float4 bv = *(float4*)&Bs[k * 68 + c0];
                    acc[0][0] += a0 * bv.x; acc[0][1] += a0 * bv.y;
                    acc[0][2] += a0 * bv.z; acc[0][3] += a0 * bv.w;
                    acc[1][0] += a1 * bv.x; acc[1][1] += a1 * bv.y;
                    acc[1][2] += a1 * bv.z; acc[1][3] += a1 * bv.w;
                }
            }
        }
        if (active) {
            float4 bb4 = *(const float4*)&bias[cbase + c0];
            float4 o0, o1;
            o0.x = acc[0][0] + bb4.x; o0.y = acc[0][1] + bb4.y;
            o0.z = acc[0][2] + bb4.z; o0.w = acc[0][3] + bb4.w;
            o1.x = acc[1][0] + bb4.x; o1.y = acc[1][1] + bb4.y;
            o1.z = acc[1][2] + bb4.z; o1.w = acc[1][3] + bb4.w;
            *(float4*)&g_g[(size_t)(rbase + r0)     * DOUT + cbase + c0] = o0;
            *(float4*)&g_g[(size_t)(rbase + r0 + 1) * DOUT + cbase + c0] = o1;
        }
    } else {
        int zi = blockIdx.x - (BB + 2048);
        int t = zi * 1024 + threadIdx.x;    // 0..32767
        g_wcount[t] = 0;
        if (t < DOUT) { g_S1[t] = 0.f; g_S2[t] = 0.f; }
    }
}

// ---------------------------------------------------------------------------
// Kernel 2: KNN via per-wave histogram select + exact f64 resolve (r5-passing)
// ---------------------------------------------------------------------------
__global__ __launch_bounds__(1024) void k_knn(
    const float* __restrict__ xyz, const float* __restrict__ out)
{
    __shared__ __align__(16) float4 pts[NN];   // 64 KB
    __shared__ unsigned hist[16][512];         // 32 KB
    __shared__ int cand[16][128];              //  8 KB
    __shared__ int cnt[16];
    const int tid = threadIdx.x, lane = tid & 63, w = tid >> 6;
    const int q = blockIdx.x * 16 + w;         // 64 blocks per batch
    const int b = blockIdx.x >> 6;
    const float* bx = xyz + (size_t)b * NN * 3;
    for (int i = 0; i < 4; ++i) {
        int p = tid + i * 1024;
        float4 v; v.x = bx[p*3]; v.y = bx[p*3+1]; v.z = bx[p*3+2]; v.w = 0.f;
        pts[p] = v;
    }
    { unsigned* h = &hist[0][0];
      #pragma unroll
      for (int i = 0; i < 8; ++i) h[tid + i * 1024] = 0u; }
    if (tid < 16) cnt[tid] = 0;
    __syncthreads();

    const float* sx = out + (size_t)BB * SS * DOUT + (size_t)q * 3;
    const float qxf = sx[0], qyf = sx[1], qzf = sx[2];
    // pass 1: histogram f32 distance bits
    unsigned minub = 0xFFFFFFFFu;
    for (int t = 0; t < 64; ++t) {
        int n = t * 64 + lane;
        float4 p = pts[n];
        float dx = qxf - p.x, dy = qyf - p.y, dz = qzf - p.z;
        float df = fmaf(dz, dz, fmaf(dy, dy, dx * dx));
        unsigned ub = __float_as_uint(df);
        minub = ub < minub ? ub : minub;
        unsigned bk = ub < 0x30800000u ? 0u : ((ub - 0x30800000u) >> 19);
        bk = bk > 511u ? 511u : bk;
        atomicAdd(&hist[w][bk], 1u);
    }
    #pragma unroll
    for (int m = 1; m < 64; m <<= 1) {
        unsigned o = __shfl_xor(minub, m);
        minub = o < minub ? o : minub;
    }
    unsigned mb = minub < 0x30800000u ? 0u : ((minub - 0x30800000u) >> 19);
    mb = mb > 511u ? 511u : mb;
    // scan own histogram row for the bucket containing rank 16
    int Tb = 511;
    unsigned base = 0;
    for (int ch = (int)(mb >> 6); ch < 8; ++ch) {
        unsigned v = hist[w][ch * 64 + lane];
        #pragma unroll
        for (int m = 1; m < 64; m <<= 1) {
            unsigned t2 = __shfl_up(v, m);
            if (lane >= m) v += t2;
        }
        unsigned tot = __shfl(v, 63);
        unsigned long long msk = __ballot(base + v >= 16u);
        if (msk) { Tb = ch * 64 + (__ffsll(msk) - 1); break; }
        base += tot;
    }
    unsigned Tcap = (unsigned)Tb + 1u; Tcap = Tcap > 511u ? 511u : Tcap;
    // pass 2: collect candidates (identical df computation => identical bits)
    for (int t = 0; t < 64; ++t) {
        int n = t * 64 + lane;
        float4 p = pts[n];
        float dx = qxf - p.x, dy = qyf - p.y, dz = qzf - p.z;
        float df = fmaf(dz, dz, fmaf(dy, dy, dx * dx));
        unsigned ub = __float_as_uint(df);
        unsigned bk = ub < 0x30800000u ? 0u : ((ub - 0x30800000u) >> 19);
        bk = bk > 511u ? 511u : bk;
        if (bk <= Tcap) {
            int slot = atomicAdd(&cnt[w], 1);
            if (slot < 128) cand[w][slot] = n;
        }
    }
    {
        #pragma clang fp contract(off)
        // wave-local LDS produced by own lanes: no block barrier needed
        int count = cnt[w]; count = count > 128 ? 128 : count;
        const double qx = (double)qxf, qy = (double)qyf, qz = (double)qzf;
        int i0 = lane < count ? cand[w][lane] : -1;
        int i1 = (lane + 64) < count ? cand[w][lane + 64] : -1;
        double d0 = 1e300, d1 = 1e300;
        if (i0 >= 0) {
            float4 p = pts[i0];
            double dx = qx - (double)p.x, dy = qy - (double)p.y, dz = qz - (double)p.z;
            double m1 = dx*dx, m2 = dy*dy, m3 = dz*dz;
            d0 = (m1 + m2) + m3;
        }
        if (i1 >= 0) {
            float4 p = pts[i1];
            double dx = qx - (double)p.x, dy = qy - (double)p.y, dz = qz - (double)p.z;
            double m1 = dx*dx, m2 = dy*dy, m3 = dz*dz;
            d1 = (m1 + m2) + m3;
        }
        int r0 = 0, r1 = 0;
        for (int i = 0; i < count; ++i) {
            double od; int oi;
            if (i < 64) { od = __shfl(d0, i);      oi = __shfl(i0, i); }
            else        { od = __shfl(d1, i - 64); oi = __shfl(i1, i - 64); }
            if ((od < d0) || (od == d0 && oi < i0)) ++r0;
            if ((od < d1) || (od == d1 && oi < i1)) ++r1;
        }
        if (i0 >= 0 && r0 < KK) {
            g_knn[(size_t)q * KK + r0] = i0;
            atomicAdd(&g_wcount[b * NN + i0], 1);
        }
        if (i1 >= 0 && r1 < KK) {
            g_knn[(size_t)q * KK + r1] = i1;
            atomicAdd(&g_wcount[b * NN + i1], 1);
        }
    }
}

// ---------------------------------------------------------------------------
// Kernel 3: weighted per-channel sums for BN stats
// ---------------------------------------------------------------------------
__global__ __launch_bounds__(256) void k_stats()
{
    int tid = threadIdx.x;
    int rbase = blockIdx.x * 128;
    float a1 = 0.f, a2 = 0.f;
    for (int i = 0; i < 128; ++i) {
        int row = rbase + i;
        int w = g_wcount[row];
        if (w) {
            float v = g_g[(size_t)row * DOUT + tid];
            float wf = (float)w;
            a1 += wf * v;
            a2 += wf * v * v;
        }
    }
    atomicAdd(&g_S1[tid], a1);
    atomicAdd(&g_S2[tid], a2);
}

// ---------------------------------------------------------------------------
// Kernel 4: per-query max over K, then BN affine + ReLU (commutes: scale>0)
// ---------------------------------------------------------------------------
__global__ __launch_bounds__(256) void k_final(
    const float* __restrict__ gamma, const float* __restrict__ beta,
    float* __restrict__ out)
{
    int w = threadIdx.x >> 6, lane = threadIdx.x & 63;
    int q = blockIdx.x * 4 + w;       // 0..8191
    int b = q >> 10;
    int c = lane * 4;
    const int* ki = g_knn + (size_t)q * KK;
    float4 m; m.x = m.y = m.z = m.w = -1e30f;
    for (int k = 0; k < KK; ++k) {
        int idx = ki[k];
        float4 v = *(const float4*)&g_g[((size_t)(b * NN + idx)) * DOUT + c];
        m.x = fmaxf(m.x, v.x); m.y = fmaxf(m.y, v.y);
        m.z = fmaxf(m.z, v.z); m.w = fmaxf(m.w, v.w);
    }
    const float inv = 1.0f / 131072.0f;
    float4 s1 = *(const float4*)&g_S1[c];
    float4 s2 = *(const float4*)&g_S2[c];
    float4 ga = *(const float4*)&gamma[c];
    float4 be = *(const float4*)&beta[c];
    float4 o;
    {
        float mean = s1.x * inv; float var = s2.x * inv - mean * mean;
        float rs = rsqrtf(var + 1e-5f);
        float t = ga.x * (m.x - mean); t = t * rs; t += be.x; o.x = fmaxf(t, 0.f);
    }
    {
        float mean = s1.y * inv; float var = s2.y * inv - mean * mean;
        float rs = rsqrtf(var + 1e-5f);
        float t = ga.y * (m.y - mean); t = t * rs; t += be.y; o.y = fmaxf(t, 0.f);
    }
    {
        float mean = s1.z * inv; float var = s2.z * inv - mean * mean;
        float rs = rsqrtf(var + 1e-5f);
        float t = ga.z * (m.z - mean); t = t * rs; t += be.z; o.z = fmaxf(t, 0.f);
    }
    {
        float mean = s1.w * inv; float var = s2.w * inv - mean * mean;
        float rs = rsqrtf(var + 1e-5f);
        float t = ga.w * (m.w - mean); t = t * rs; t += be.w; o.w = fmaxf(t, 0.f);
    }
    *(float4*)&out[(size_t)q * DOUT + c] = o;
}

extern "C" void kernel_launch(void* const* d_in, const int* in_sizes, int n_in,
                              void* d_out, int out_size, void* d_ws, size_t ws_size,
                              hipStream_t stream) {
    (void)in_sizes; (void)n_in; (void)out_size; (void)d_ws; (void)ws_size;
    const float* feat  = (const float*)d_in[0];
    const float* xyz   = (const float*)d_in[1];
    const float* W     = (const float*)d_in[2];
    const float* bias  = (const float*)d_in[3];
    const float* gamma = (const float*)d_in[4];
    const float* beta  = (const float*)d_in[5];
    float* out = (float*)d_out;

    k_fused1<<<BB + 2048 + 32, 1024, 0, stream>>>(feat, xyz, W, bias, out);
    k_knn   <<<BB * SS / 16, 1024, 0, stream>>>(xyz, out);
    k_stats <<<256, 256, 0, stream>>>();
    k_final <<<2048, 256, 0, stream>>>(gamma, beta, out);
}

// Round 12
// 1004.826 us; speedup vs baseline: 1.2830x; 1.2830x over previous
//
#include <hip/hip_runtime.h>
#include <hip/hip_bf16.h>

#define BB 8
#define NN 4096
#define DIN 128
#define DOUT 256
#define SS 1024
#define KK 16

// Workspace in device globals: immune to ws_size, graph-capture-safe.
__device__ float g_g[(size_t)BB * NN * DOUT];     // 32 MB: g = feat @ W^T + b
__device__ int   g_knn[BB * SS * KK];
__device__ int   g_wcount[BB * NN];
__device__ float g_S1[DOUT];
__device__ float g_S2[DOUT];

typedef float f32x2 __attribute__((ext_vector_type(2)));

__device__ __forceinline__ unsigned long long umax64(unsigned long long a, unsigned long long b) {
    return a > b ? a : b;
}
__device__ __forceinline__ f32x2 pk_add(f32x2 a, f32x2 b) {
    f32x2 d; asm("v_pk_add_f32 %0, %1, %2" : "=v"(d) : "v"(a), "v"(b)); return d;
}
__device__ __forceinline__ f32x2 pk_mul(f32x2 a, f32x2 b) {
    f32x2 d; asm("v_pk_mul_f32 %0, %1, %2" : "=v"(d) : "v"(a), "v"(b)); return d;
}
__device__ __forceinline__ f32x2 pk_fma(f32x2 a, f32x2 b, f32x2 c) {
    f32x2 d; asm("v_pk_fma_f32 %0, %1, %2, %3" : "=v"(d) : "v"(a), "v"(b), "v"(c)); return d;
}

// ---------------------------------------------------------------------------
// Kernel 1 (512 threads): blocks [0,8)   : FPS per batch (8 pts/thread, r7
//                            config; ONLY change: zero global stores in the
//                            loop -> the pre-barrier vmcnt(0) drain is free)
//                         blocks [8,2056): GEMM g = feat @ W^T + b
//                         blocks [2056,2088): zero wcount / S1 / S2
// ---------------------------------------------------------------------------
__global__ __launch_bounds__(512) void k_fused1(
    const float* __restrict__ feat, const float* __restrict__ xyz,
    const float* __restrict__ W, const float* __restrict__ bias,
    float* __restrict__ out)
{
    __shared__ __align__(16) float smem[16384]; // xyz as float4[4096] OR gemm tiles
    __shared__ __align__(16) unsigned long long swk64[2][8];
    __shared__ unsigned short win_idx[SS];

    if (blockIdx.x < BB) {
        #pragma clang fp contract(off)
        // FPS. dist64 updates are bit-identical to numpy float64:
        // dx = (f64)x - (f64)lx; m = dx*dx (unfused); d = (m1+m2)+m3; min.
        // Selection key: top-52 bits of f64 dist | (4095-idx): argmax with
        // first-occurrence tie-break (np.argmax semantics).
        const int b = blockIdx.x, tid = threadIdx.x;
        const float* bx = xyz + (size_t)b * NN * 3;
        for (int i = 0; i < 8; ++i) {
            int p = tid + i * 512;
            float4 v; v.x = bx[p*3]; v.y = bx[p*3+1]; v.z = bx[p*3+2]; v.w = 0.f;
            ((float4*)smem)[p] = v;
        }
        if (tid == 0) win_idx[0] = 0;
        __syncthreads();
        f32x2 px2[4], py2[4], pz2[4];
        double dist64[8];
        float thr[8];
        unsigned long long key[8];
        const int gbase = tid * 8;
        const unsigned long long D0 =
            ((unsigned long long)__double_as_longlong(1e10)) & ~0xFFFULL;
        const float THR0 = __uint_as_float(__float_as_uint(1e10f) + 16u);
        #pragma unroll
        for (int pp = 0; pp < 4; ++pp) {
            float4 v0 = ((float4*)smem)[gbase + 2*pp];
            float4 v1 = ((float4*)smem)[gbase + 2*pp + 1];
            px2[pp].x = v0.x; px2[pp].y = v1.x;
            py2[pp].x = v0.y; py2[pp].y = v1.y;
            pz2[pp].x = v0.z; pz2[pp].y = v1.z;
            dist64[2*pp]   = 1e10; dist64[2*pp+1] = 1e10;
            thr[2*pp] = THR0;      thr[2*pp+1] = THR0;
            key[2*pp]   = D0 | (unsigned long long)(4095 - (gbase + 2*pp));
            key[2*pp+1] = D0 | (unsigned long long)(4095 - (gbase + 2*pp + 1));
        }
        float4 c0v = ((float4*)smem)[0];
        float lxf = c0v.x, lyf = c0v.y, lzf = c0v.z;
        for (int s = 1; s < SS; ++s) {
            const int sl = s & 1;
            const double lxd = (double)lxf, lyd = (double)lyf, lzd = (double)lzf;
            f32x2 nlx; nlx.x = -lxf; nlx.y = -lxf;
            f32x2 nly; nly.x = -lyf; nly.y = -lyf;
            f32x2 nlz; nlz.x = -lzf; nlz.y = -lzf;
            #pragma unroll
            for (int pp = 0; pp < 4; ++pp) {
                f32x2 dx = pk_add(px2[pp], nlx);
                f32x2 dy = pk_add(py2[pp], nly);
                f32x2 dz = pk_add(pz2[pp], nlz);
                f32x2 d2 = pk_mul(dx, dx);
                d2 = pk_fma(dy, dy, d2);
                d2 = pk_fma(dz, dz, d2);
                // gate: enter exact path only if d32 < f32(dist64)+16ulp
                if (d2.x < thr[2*pp]) {
                    const int r = 2*pp;
                    double ddx = (double)px2[pp].x - lxd;
                    double ddy = (double)py2[pp].x - lyd;
                    double ddz = (double)pz2[pp].x - lzd;
                    double m1 = ddx*ddx, m2 = ddy*ddy, m3 = ddz*ddz;
                    double d = (m1 + m2) + m3;
                    if (d < dist64[r]) {
                        dist64[r] = d;
                        thr[r] = __uint_as_float(__float_as_uint((float)d) + 16u);
                        key[r] = (((unsigned long long)__double_as_longlong(d)) & ~0xFFFULL)
                                 | (unsigned long long)(4095 - (gbase + r));
                    }
                }
                if (d2.y < thr[2*pp+1]) {
                    const int r = 2*pp + 1;
                    double ddx = (double)px2[pp].y - lxd;
                    double ddy = (double)py2[pp].y - lyd;
                    double ddz = (double)pz2[pp].y - lzd;
                    double m1 = ddx*ddx, m2 = ddy*ddy, m3 = ddz*ddz;
                    double d = (m1 + m2) + m3;
                    if (d < dist64[r]) {
                        dist64[r] = d;
                        thr[r] = __uint_as_float(__float_as_uint((float)d) + 16u);
                        key[r] = (((unsigned long long)__double_as_longlong(d)) & ~0xFFFULL)
                                 | (unsigned long long)(4095 - (gbase + r));
                    }
                }
            }
            // --- per-thread 8 -> 1 key max ---
            unsigned long long kk;
            {
                unsigned long long a0 = umax64(key[0], key[1]);
                unsigned long long a1 = umax64(key[2], key[3]);
                unsigned long long a2 = umax64(key[4], key[5]);
                unsigned long long a3 = umax64(key[6], key[7]);
                kk = umax64(umax64(a0, a1), umax64(a2, a3));
            }
            // --- wave64 max via DPP (VALU latency, no ds_swizzle) ---
#define DPP64(CTRL) { \
    int _lo = __builtin_amdgcn_update_dpp(0, (int)(unsigned)kk, CTRL, 0xf, 0xf, true); \
    int _hi = __builtin_amdgcn_update_dpp(0, (int)(unsigned)(kk >> 32), CTRL, 0xf, 0xf, true); \
    unsigned long long _o = (((unsigned long long)(unsigned)_hi) << 32) | (unsigned)_lo; \
    if (_o > kk) kk = _o; }
            DPP64(0x111)  // row_shr:1
            DPP64(0x112)  // row_shr:2
            DPP64(0x114)  // row_shr:4
            DPP64(0x118)  // row_shr:8
            DPP64(0x142)  // row_bcast:15
            DPP64(0x143)  // row_bcast:31
#undef DPP64
            if ((tid & 63) == 63) swk64[sl][tid >> 6] = kk;
            __syncthreads();
            const unsigned long long* sw = swk64[sl];
            ulonglong2 s01 = ((const ulonglong2*)sw)[0];
            ulonglong2 s23 = ((const ulonglong2*)sw)[1];
            ulonglong2 s45 = ((const ulonglong2*)sw)[2];
            ulonglong2 s67 = ((const ulonglong2*)sw)[3];
            unsigned long long kmax = umax64(
                umax64(umax64(s01.x, s01.y), umax64(s23.x, s23.y)),
                umax64(umax64(s45.x, s45.y), umax64(s67.x, s67.y)));
            int widx = 4095 - (int)(kmax & 0xFFFULL);
            float4 c = ((float4*)smem)[widx];
            lxf = c.x; lyf = c.y; lzf = c.z;
            if (tid == 0) win_idx[s] = (unsigned short)widx;
        }
        // epilogue: write all sampled xyz (winner coords) to out
        __syncthreads();
        float* oxyz = out + (size_t)BB * SS * DOUT;
        for (int i = tid; i < SS; i += 512) {
            int wi = win_idx[i];
            float4 c = ((float4*)smem)[wi];
            oxyz[(size_t)(b*SS+i)*3]   = c.x;
            oxyz[(size_t)(b*SS+i)*3+1] = c.y;
            oxyz[(size_t)(b*SS+i)*3+2] = c.z;
        }
    } else if (blockIdx.x < BB + 2048) {
        // GEMM: BM=64, BN=64, BK=32, 512 threads, 2x4 per thread (validated r2)
        int gi = blockIdx.x - BB;
        int mt = gi & 511, nt = gi >> 9;
        int rbase = mt * 64, cbase = nt * 64;
        float* As = smem;            // [64][36]
        float* Bs = smem + 64 * 36;  // [32][68]
        int tid = threadIdx.x;
        int tx = tid & 15, ty = tid >> 4;
        int c0 = tx * 4, r0 = ty * 2;
        int lr = tid >> 3;          // 0..63
        int lk = (tid & 7) * 4;     // 0..28
        float acc[2][4] = {{0.f,0.f,0.f,0.f},{0.f,0.f,0.f,0.f}};
        for (int kc = 0; kc < 4; ++kc) {
            __syncthreads();
            float4 av = *(const float4*)&feat[(size_t)(rbase + lr) * DIN + kc*32 + lk];
            *(float4*)&As[lr * 36 + lk] = av;
            float4 wv = *(const float4*)&W[(size_t)(cbase + lr) * DIN + kc*32 + lk];
            Bs[(lk+0)*68 + lr] = wv.x;
            Bs[(lk+1)*68 + lr] = wv.y;
            Bs[(lk+2)*68 + lr] = wv.z;
            Bs[(lk+3)*68 + lr] = wv.w;
            __syncthreads();
            const float* Ar0 = &As[r0 * 36];
            const float* Ar1 = Ar0 + 36;
            #pragma unroll
            for (int k = 0; k < 32; ++k) {
                float a0 = Ar0[k], a1 = Ar1[k];
                float4 bv = *(float4*)&Bs[k * 68 + c0];
                acc[0][0] += a0 * bv.x; acc[0][1] += a0 * bv.y;
                acc[0][2] += a0 * bv.z; acc[0][3] += a0 * bv.w;
                acc[1][0] += a1 * bv.x; acc[1][1] += a1 * bv.y;
                acc[1][2] += a1 * bv.z; acc[1][3] += a1 * bv.w;
            }
        }
        float4 bb4 = *(const float4*)&bias[cbase + c0];
        float4 o0, o1;
        o0.x = acc[0][0] + bb4.x; o0.y = acc[0][1] + bb4.y;
        o0.z = acc[0][2] + bb4.z; o0.w = acc[0][3] + bb4.w;
        o1.x = acc[1][0] + bb4.x; o1.y = acc[1][1] + bb4.y;
        o1.z = acc[1][2] + bb4.z; o1.w = acc[1][3] + bb4.w;
        *(float4*)&g_g[(size_t)(rbase + r0)     * DOUT + cbase + c0] = o0;
        *(float4*)&g_g[(size_t)(rbase + r0 + 1) * DOUT + cbase + c0] = o1;
    } else {
        int zi = blockIdx.x - (BB + 2048);
        int t = zi * 512 + threadIdx.x;     // 0..16383
        g_wcount[t] = 0;
        g_wcount[t + 16384] = 0;
        if (t < DOUT) { g_S1[t] = 0.f; g_S2[t] = 0.f; }
    }
}

// ---------------------------------------------------------------------------
// Kernel 2: KNN via per-wave histogram select + exact f64 resolve (r5-passing)
// ---------------------------------------------------------------------------
__global__ __launch_bounds__(1024) void k_knn(
    const float* __restrict__ xyz, const float* __restrict__ out)
{
    __shared__ __align__(16) float4 pts[NN];   // 64 KB
    __shared__ unsigned hist[16][512];         // 32 KB
    __shared__ int cand[16][128];              //  8 KB
    __shared__ int cnt[16];
    const int tid = threadIdx.x, lane = tid & 63, w = tid >> 6;
    const int q = blockIdx.x * 16 + w;         // 64 blocks per batch
    const int b = blockIdx.x >> 6;
    const float* bx = xyz + (size_t)b * NN * 3;
    for (int i = 0; i < 4; ++i) {
        int p = tid + i * 1024;
        float4 v; v.x = bx[p*3]; v.y = bx[p*3+1]; v.z = bx[p*3+2]; v.w = 0.f;
        pts[p] = v;
    }
    { unsigned* h = &hist[0][0];
      #pragma unroll
      for (int i = 0; i < 8; ++i) h[tid + i * 1024] = 0u; }
    if (tid < 16) cnt[tid] = 0;
    __syncthreads();

    const float* sx = out + (size_t)BB * SS * DOUT + (size_t)q * 3;
    const float qxf = sx[0], qyf = sx[1], qzf = sx[2];
    // pass 1: histogram f32 distance bits
    unsigned minub = 0xFFFFFFFFu;
    for (int t = 0; t < 64; ++t) {
        int n = t * 64 + lane;
        float4 p = pts[n];
        float dx = qxf - p.x, dy = qyf - p.y, dz = qzf - p.z;
        float df = fmaf(dz, dz, fmaf(dy, dy, dx * dx));
        unsigned ub = __float_as_uint(df);
        minub = ub < minub ? ub : minub;
        unsigned bk = ub < 0x30800000u ? 0u : ((ub - 0x30800000u) >> 19);
        bk = bk > 511u ? 511u : bk;
        atomicAdd(&hist[w][bk], 1u);
    }
    #pragma unroll
    for (int m = 1; m < 64; m <<= 1) {
        unsigned o = __shfl_xor(minub, m);
        minub = o < minub ? o : minub;
    }
    unsigned mb = minub < 0x30800000u ? 0u : ((minub - 0x30800000u) >> 19);
    mb = mb > 511u ? 511u : mb;
    // scan own histogram row for the bucket containing rank 16
    int Tb = 511;
    unsigned base = 0;
    for (int ch = (int)(mb >> 6); ch < 8; ++ch) {
        unsigned v = hist[w][ch * 64 + lane];
        #pragma unroll
        for (int m = 1; m < 64; m <<= 1) {
            unsigned t2 = __shfl_up(v, m);
            if (lane >= m) v += t2;
        }
        unsigned tot = __shfl(v, 63);
        unsigned long long msk = __ballot(base + v >= 16u);
        if (msk) { Tb = ch * 64 + (__ffsll(msk) - 1); break; }
        base += tot;
    }
    unsigned Tcap = (unsigned)Tb + 1u; Tcap = Tcap > 511u ? 511u : Tcap;
    // pass 2: collect candidates (identical df computation => identical bits)
    for (int t = 0; t < 64; ++t) {
        int n = t * 64 + lane;
        float4 p = pts[n];
        float dx = qxf - p.x, dy = qyf - p.y, dz = qzf - p.z;
        float df = fmaf(dz, dz, fmaf(dy, dy, dx * dx));
        unsigned ub = __float_as_uint(df);
        unsigned bk = ub < 0x30800000u ? 0u : ((ub - 0x30800000u) >> 19);
        bk = bk > 511u ? 511u : bk;
        if (bk <= Tcap) {
            int slot = atomicAdd(&cnt[w], 1);
            if (slot < 128) cand[w][slot] = n;
        }
    }
    {
        #pragma clang fp contract(off)
        // wave-local LDS produced by own lanes: no block barrier needed
        int count = cnt[w]; count = count > 128 ? 128 : count;
        const double qx = (double)qxf, qy = (double)qyf, qz = (double)qzf;
        int i0 = lane < count ? cand[w][lane] : -1;
        int i1 = (lane + 64) < count ? cand[w][lane + 64] : -1;
        double d0 = 1e300, d1 = 1e300;
        if (i0 >= 0) {
            float4 p = pts[i0];
            double dx = qx - (double)p.x, dy = qy - (double)p.y, dz = qz - (double)p.z;
            double m1 = dx*dx, m2 = dy*dy, m3 = dz*dz;
            d0 = (m1 + m2) + m3;
        }
        if (i1 >= 0) {
            float4 p = pts[i1];
            double dx = qx - (double)p.x, dy = qy - (double)p.y, dz = qz - (double)p.z;
            double m1 = dx*dx, m2 = dy*dy, m3 = dz*dz;
            d1 = (m1 + m2) + m3;
        }
        int r0 = 0, r1 = 0;
        for (int i = 0; i < count; ++i) {
            double od; int oi;
            if (i < 64) { od = __shfl(d0, i);      oi = __shfl(i0, i); }
            else        { od = __shfl(d1, i - 64); oi = __shfl(i1, i - 64); }
            if ((od < d0) || (od == d0 && oi < i0)) ++r0;
            if ((od < d1) || (od == d1 && oi < i1)) ++r1;
        }
        if (i0 >= 0 && r0 < KK) {
            g_knn[(size_t)q * KK + r0] = i0;
            atomicAdd(&g_wcount[b * NN + i0], 1);
        }
        if (i1 >= 0 && r1 < KK) {
            g_knn[(size_t)q * KK + r1] = i1;
            atomicAdd(&g_wcount[b * NN + i1], 1);
        }
    }
}

// ---------------------------------------------------------------------------
// Kernel 3: weighted per-channel sums for BN stats
// ---------------------------------------------------------------------------
__global__ __launch_bounds__(256) void k_stats()
{
    int tid = threadIdx.x;
    int rbase = blockIdx.x * 128;
    float a1 = 0.f, a2 = 0.f;
    for (int i = 0; i < 128; ++i) {
        int row = rbase + i;
        int w = g_wcount[row];
        if (w) {
            float v = g_g[(size_t)row * DOUT + tid];
            float wf = (float)w;
            a1 += wf * v;
            a2 += wf * v * v;
        }
    }
    atomicAdd(&g_S1[tid], a1);
    atomicAdd(&g_S2[tid], a2);
}

// ---------------------------------------------------------------------------
// Kernel 4: per-query max over K, then BN affine + ReLU (commutes: scale>0)
// ---------------------------------------------------------------------------
__global__ __launch_bounds__(256) void k_final(
    const float* __restrict__ gamma, const float* __restrict__ beta,
    float* __restrict__ out)
{
    int w = threadIdx.x >> 6, lane = threadIdx.x & 63;
    int q = blockIdx.x * 4 + w;       // 0..8191
    int b = q >> 10;
    int c = lane * 4;
    const int* ki = g_knn + (size_t)q * KK;
    float4 m; m.x = m.y = m.z = m.w = -1e30f;
    for (int k = 0; k < KK; ++k) {
        int idx = ki[k];
        float4 v = *(const float4*)&g_g[((size_t)(b * NN + idx)) * DOUT + c];
        m.x = fmaxf(m.x, v.x); m.y = fmaxf(m.y, v.y);
        m.z = fmaxf(m.z, v.z); m.w = fmaxf(m.w, v.w);
    }
    const float inv = 1.0f / 131072.0f;
    float4 s1 = *(const float4*)&g_S1[c];
    float4 s2 = *(const float4*)&g_S2[c];
    float4 ga = *(const float4*)&gamma[c];
    float4 be = *(const float4*)&beta[c];
    float4 o;
    {
        float mean = s1.x * inv; float var = s2.x * inv - mean * mean;
        float rs = rsqrtf(var + 1e-5f);
        float t = ga.x * (m.x - mean); t = t * rs; t += be.x; o.x = fmaxf(t, 0.f);
    }
    {
        float mean = s1.y * inv; float var = s2.y * inv - mean * mean;
        float rs = rsqrtf(var + 1e-5f);
        float t = ga.y * (m.y - mean); t = t * rs; t += be.y; o.y = fmaxf(t, 0.f);
    }
    {
        float mean = s1.z * inv; float var = s2.z * inv - mean * mean;
        float rs = rsqrtf(var + 1e-5f);
        float t = ga.z * (m.z - mean); t = t * rs; t += be.z; o.z = fmaxf(t, 0.f);
    }
    {
        float mean = s1.w * inv; float var = s2.w * inv - mean * mean;
        float rs = rsqrtf(var + 1e-5f);
        float t = ga.w * (m.w - mean); t = t * rs; t += be.w; o.w = fmaxf(t, 0.f);
    }
    *(float4*)&out[(size_t)q * DOUT + c] = o;
}

extern "C" void kernel_launch(void* const* d_in, const int* in_sizes, int n_in,
                              void* d_out, int out_size, void* d_ws, size_t ws_size,
                              hipStream_t stream) {
    (void)in_sizes; (void)n_in; (void)out_size; (void)d_ws; (void)ws_size;
    const float* feat  = (const float*)d_in[0];
    const float* xyz   = (const float*)d_in[1];
    const float* W     = (const float*)d_in[2];
    const float* bias  = (const float*)d_in[3];
    const float* gamma = (const float*)d_in[4];
    const float* beta  = (const float*)d_in[5];
    float* out = (float*)d_out;

    k_fused1<<<BB + 2048 + 32, 512, 0, stream>>>(feat, xyz, W, bias, out);
    k_knn   <<<BB * SS / 16, 1024, 0, stream>>>(xyz, out);
    k_stats <<<256, 256, 0, stream>>>();
    k_final <<<2048, 256, 0, stream>>>(gamma, beta, out);
}